// Round 10
// baseline (1561.847 us; speedup 1.0000x reference)
//
#include <hip/hip_runtime.h>
#include <stdint.h>
#include <stddef.h>

// ---------------------------------------------------------------------------
// CSTreeLSTM on gfx950. Levels 1,16,256,4096,65536 (x offsets 0,1,17,273,4369).
// Round 18: persistent coop-tail kernel. The 8-launch post-leaf chain
// (fc4||l3g -> final3 -> fc2||l2g -> final2 -> fcdot -> lvl1_tail ->
// dot_merge -> root_tail) is ONE 768-block kernel with a device-scope
// sense-reversing grid barrier (atomics + threadfence; 768 = 256CU x 3
// blocks guaranteed co-resident by launch_bounds(256,3) + 40KB LDS).
// All phase bodies r17-verbatim, grid-strided. conv + leaf_fx unchanged.
// ---------------------------------------------------------------------------

typedef __bf16 bf16x8 __attribute__((ext_vector_type(8)));
typedef float  f32x4  __attribute__((ext_vector_type(4)));
typedef void __attribute__((address_space(3))) lds_void_t;
typedef void __attribute__((address_space(1))) gbl_void_t;

__device__ __forceinline__ uint16_t f2bf(float f) {
  union { __bf16 b; uint16_t u; } v;
  v.b = (__bf16)f;              // RTNE, compiler emits v_cvt_pk_bf16_f32
  return v.u;
}
__device__ __forceinline__ float bf2f(uint16_t u) {
  union { uint32_t u; float f; } v; v.u = (uint32_t)u << 16;
  return v.f;
}
__device__ __forceinline__ float sig_(float x) {
  return __builtin_amdgcn_rcpf(1.0f + __expf(-x));
}
__device__ __forceinline__ float tanh_(float x) {
  return __builtin_fmaf(2.f,
      __builtin_amdgcn_rcpf(1.f + __expf(-2.f * x)), -1.f);
}

// ---- device-scope grid barrier (sense-reversing; bar[0]=cnt, bar[1]=gen) ---
#define NBLK 768u
__device__ __forceinline__ void gbar(unsigned* bar) {
  __syncthreads();
  if (threadIdx.x == 0) {
    __threadfence();                                     // release
    unsigned g = __hip_atomic_load(bar + 1, __ATOMIC_RELAXED,
                                   __HIP_MEMORY_SCOPE_AGENT);
    unsigned a = __hip_atomic_fetch_add(bar, 1u, __ATOMIC_ACQ_REL,
                                        __HIP_MEMORY_SCOPE_AGENT) + 1u;
    if (a == NBLK) {
      __hip_atomic_store(bar, 0u, __ATOMIC_RELAXED, __HIP_MEMORY_SCOPE_AGENT);
      __hip_atomic_fetch_add(bar + 1, 1u, __ATOMIC_RELEASE,
                             __HIP_MEMORY_SCOPE_AGENT);
    } else {
      long spins = 0;
      while (__hip_atomic_load(bar + 1, __ATOMIC_ACQUIRE,
                               __HIP_MEMORY_SCOPE_AGENT) == g) {
        if (++spins > (1L << 28)) break;                 // safety valve
        __builtin_amdgcn_s_sleep(8);
      }
    }
    __threadfence();                                     // acquire
  }
  __syncthreads();
}

// ---- merged convert: all x rows + 4 weight matrices ------------------------
__global__ void k_conv_all(const float4* __restrict__ x,
                           ushort4* __restrict__ xdst, long n4x,
                           const float4* __restrict__ w0,
                           const float4* __restrict__ w1,
                           const float4* __restrict__ w2,
                           const float4* __restrict__ w3,
                           ushort4* __restrict__ wdst) {
  const long per4 = (long)512 * 1024 / 4;
  const long total = n4x + 4 * per4;
  long i = blockIdx.x * (long)blockDim.x + threadIdx.x;
  long stride = (long)gridDim.x * blockDim.x;
  for (; i < total; i += stride) {
    float4 v;
    ushort4* d;
    if (i < n4x) {
      v = x[i];
      d = xdst + i;
    } else {
      long j = i - n4x;
      long seg = j / per4, off2 = j - seg * per4;
      const float4* s = (seg == 0) ? w0 : (seg == 1) ? w1
                       : (seg == 2) ? w2 : w3;
      v = s[off2];
      d = wdst + j;
    }
    ushort4 r;
    r.x = f2bf(v.x); r.y = f2bf(v.y); r.z = f2bf(v.z); r.w = f2bf(v.w);
    *d = r;
  }
}

#define BM 128
#define BN 128
#define BK 32

// ---- merged leaf k_level + FxAll gemm_bt (r17 verbatim) --------------------
__global__ __launch_bounds__(256, 3)
void k_leaf_fx(const uint16_t* __restrict__ Xleaf,
               const uint16_t* __restrict__ Wg,
               const float* __restrict__ bi, const float* __restrict__ bo,
               const float* __restrict__ bu,
               uint16_t* __restrict__ Cbf,
               const uint16_t* __restrict__ Xnext,
               uint16_t* __restrict__ xh_next,
               const uint16_t* __restrict__ Xbf,
               const uint16_t* __restrict__ Wf,
               float* __restrict__ FxAll) {
  __shared__ uint16_t smem[20480];                       // 40 KB pool
  const int tid = threadIdx.x, lane = tid & 63, wave = tid >> 6;
  const int lrow = lane & 15, quad = lane >> 4;

  if (blockIdx.x < 4096) {
    uint16_t* As = smem;
    uint16_t* Bs = smem + 8192;
    const int wm = (wave >> 1) * 64, wn = (wave & 1) * 32;
    long tm, tn;
    {
      int b = blockIdx.x;
      int x = b & 7, j = b >> 3, per = 64;       // nTm=512
      tn = j & 7; tm = (long)x * per + (j >> 3);
    }
    f32x4 acc[3][4][2] = {};
    const int srow = lane >> 3;
    const int scol = (((lane & 7) ^ srow) << 3);
    const int rsw = lrow & 7;
    const int pc[2] = { ((0 + quad) ^ rsw) << 3, ((4 + quad) ^ rsw) << 3 };

    for (int k0 = 0; k0 < 512; k0 += 64) {
#pragma unroll
      for (int j = 0; j < 4; ++j) {
        int grp = wave * 4 + j;
        int row = grp * 8 + srow;
        const uint16_t* gp = Xleaf + (tm * 128 + row) * 512L + k0 + scol;
        __builtin_amdgcn_global_load_lds((gbl_void_t*)(uintptr_t)gp,
            (lds_void_t*)&As[grp * 512], 16, 0, 0);
      }
#pragma unroll
      for (int j = 0; j < 6; ++j) {
        int cc = wave * 6 + j;
        int g  = cc >> 3;
        long grow = (long)g * 512 + tn * 64 + (cc & 7) * 8 + srow;
        const uint16_t* gp = Wg + grow * 1024 + k0 + scol;
        __builtin_amdgcn_global_load_lds((gbl_void_t*)(uintptr_t)gp,
            (lds_void_t*)&Bs[cc * 512], 16, 0, 0);
      }
      __syncthreads();
#pragma unroll
      for (int h = 0; h < 2; ++h) {
        bf16x8 a[4];
#pragma unroll
        for (int f = 0; f < 4; ++f)
          a[f] = *(const bf16x8*)&As[(wm + f * 16 + lrow) * 64 + pc[h]];
#pragma unroll
        for (int g = 0; g < 3; ++g) {
          bf16x8 b0 = *(const bf16x8*)&Bs[(g * 64 + wn + lrow) * 64 + pc[h]];
          bf16x8 b1 = *(const bf16x8*)&Bs[(g * 64 + wn + 16 + lrow) * 64 +
                                          pc[h]];
#pragma unroll
          for (int fm = 0; fm < 4; ++fm) {
            acc[g][fm][0] = __builtin_amdgcn_mfma_f32_16x16x32_bf16(
                a[fm], b0, acc[g][fm][0], 0, 0, 0);
            acc[g][fm][1] = __builtin_amdgcn_mfma_f32_16x16x32_bf16(
                a[fm], b1, acc[g][fm][1], 0, 0, 0);
          }
        }
      }
      __syncthreads();
    }
#pragma unroll
    for (int fn = 0; fn < 2; ++fn) {
      long col = tn * 64 + wn + fn * 16 + lrow;
      float biv = bi[col], bov = bo[col], buv = bu[col];
#pragma unroll
      for (int fm = 0; fm < 4; ++fm) {
        long row0 = tm * 128 + wm + fm * 16 + quad * 4;
        long pg   = tm * 8 + (wm >> 4) + fm;
        float hs = 0.f;
#pragma unroll
        for (int r = 0; r < 4; ++r) {
          long row = row0 + r;
          float iv = sig_(acc[0][fm][fn][r] + biv);
          float ov = sig_(acc[1][fm][fn][r] + bov);
          float uv = tanh_(acc[2][fm][fn][r] + buv);
          float c  = iv * uv;
          Cbf[row * 512 + col] = f2bf(c);
          hs += ov * tanh_(c);
        }
        hs += __shfl_xor(hs, 16, 64);
        hs += __shfl_xor(hs, 32, 64);
        if (quad == 0) {
          xh_next[pg * 1024 + col]       = Xnext[pg * 512 + col];
          xh_next[pg * 1024 + 512 + col] = f2bf(hs);
        }
      }
    }
  } else {
    uint16_t* As = smem;
    uint16_t* Bs = smem + 4096;
    const int wm = (wave >> 1) * 64, wn = (wave & 1) * 64;
    int bid2 = (int)blockIdx.x - 4096;
    const long tm = bid2 % 35, tn = bid2 / 35;
    f32x4 acc[4][4] = {};
    const int srow2 = lane >> 2, scol2 = (lane & 3) * 8;
    for (int k0 = 0; k0 < 512; k0 += BK) {
#pragma unroll
      for (int i = 0; i < 2; ++i) {
        int row = i * 64 + wave * 16 + srow2;
        const uint16_t* gp = Xbf + (tm * BM + row) * 512L + k0 + scol2;
        __builtin_amdgcn_global_load_lds((gbl_void_t*)(uintptr_t)gp,
            (lds_void_t*)&As[i * 2048 + wave * 512], 16, 0, 0);
      }
#pragma unroll
      for (int i = 0; i < 2; ++i) {
        int row = i * 64 + wave * 16 + srow2;
        const uint16_t* gp = Wf + (tn * BN + row) * 1024L + k0 + scol2;
        __builtin_amdgcn_global_load_lds((gbl_void_t*)(uintptr_t)gp,
            (lds_void_t*)&Bs[i * 2048 + wave * 512], 16, 0, 0);
      }
      __syncthreads();
      bf16x8 a[4], b[4];
#pragma unroll
      for (int f = 0; f < 4; ++f)
        a[f] = *(const bf16x8*)&As[(wm + f * 16 + lrow) * BK + quad * 8];
#pragma unroll
      for (int f = 0; f < 4; ++f)
        b[f] = *(const bf16x8*)&Bs[(wn + f * 16 + lrow) * BK + quad * 8];
#pragma unroll
      for (int fm = 0; fm < 4; ++fm)
#pragma unroll
        for (int fn = 0; fn < 4; ++fn)
          acc[fm][fn] = __builtin_amdgcn_mfma_f32_16x16x32_bf16(
              a[fm], b[fn], acc[fm][fn], 0, 0, 0);
      __syncthreads();
    }
#pragma unroll
    for (int fm = 0; fm < 4; ++fm)
#pragma unroll
      for (int fn = 0; fn < 4; ++fn) {
        long col  = tn * BN + wn + fn * 16 + lrow;
        long row0 = tm * BM + wm + fm * 16 + quad * 4;
#pragma unroll
        for (int r = 0; r < 4; ++r)
          FxAll[(row0 + r) * 512 + col] = acc[fm][fn][r];
      }
  }
}

// ---- coop args -------------------------------------------------------------
struct CoopArgs {
  const uint16_t* Cbf;      // leaf C
  const uint16_t* Wfc;      // Wf + 512 (bf16, ldb 1024)
  const float*    FxAll;    // base
  const float*    bfb;      // wf_b
  float*          Fpart;
  const uint16_t* xhA;
  const uint16_t* Wg;
  float*          G3;
  const float*    bi; const float* bo; const float* bu;
  uint16_t*       CbfU;
  const uint16_t* Xbf;      // base
  uint16_t*       xhB;
  uint16_t*       CbfU2;
  uint16_t*       xhC;
  float*          Gf;
  float*          CupA;
  const float*    WfF;      // wf_w + 512 (fp32)
  float*          Fc;
  float*          H; float* Cv;
  unsigned*       bar;
};

// ---- level_final body (r17 verbatim, p/tid-parameterized) ------------------
__device__ __forceinline__ void level_final_body(
    int p, int tid, const float* G3, const float* Fpart,
    const float* bi, const float* bo, const float* bu,
    uint16_t* Cbf_out, const uint16_t* Xnext, uint16_t* xh_next) {
  const int hq = (tid & 127) << 2;
  float4 b_i = *(const float4*)(bi + hq);
  float4 b_o = *(const float4*)(bo + hq);
  float4 b_u = *(const float4*)(bu + hq);
  const float* bip = &b_i.x; const float* bop = &b_o.x;
  const float* bup = &b_u.x;
  float hs[4] = {0.f, 0.f, 0.f, 0.f};
#pragma unroll 4
  for (int k = 0; k < 16; ++k) {
    long row = (long)p * 16 + k;
    float4 gi = *(const float4*)(G3 + row * 1536 + hq);
    float4 go = *(const float4*)(G3 + row * 1536 + 512 + hq);
    float4 gu = *(const float4*)(G3 + row * 1536 + 1024 + hq);
    float4 fp = *(const float4*)(Fpart + row * 512 + hq);
    const float* gip = &gi.x; const float* gop = &go.x;
    const float* gup = &gu.x; const float* fpp = &fp.x;
    ushort4 cw; unsigned short* cwp = &cw.x;
#pragma unroll
    for (int j = 0; j < 4; ++j) {
      float iv = sig_(gip[j] + bip[j]);
      float ov = sig_(gop[j] + bop[j]);
      float uv = tanh_(gup[j] + bup[j]);
      float c  = iv * uv + fpp[j];
      cwp[j] = f2bf(c);
      hs[j] += ov * tanh_(c);
    }
    *(ushort4*)(Cbf_out + row * 512 + hq) = cw;
  }
  *(ushort4*)(xh_next + (long)p * 1024 + hq) =
      *(const ushort4*)(Xnext + (long)p * 512 + hq);
  ushort4 hw = {f2bf(hs[0]), f2bf(hs[1]), f2bf(hs[2]), f2bf(hs[3])};
  *(ushort4*)(xh_next + (long)p * 1024 + 512 + hq) = hw;
}

// ---- persistent coop tail: 8 phases, 7 grid barriers -----------------------
__global__ __launch_bounds__(256, 3)
void k_coop(CoopArgs a) {
  __shared__ __align__(16) unsigned char smem_raw[40960];
  uint16_t* smem = (uint16_t*)smem_raw;
  const int tid = threadIdx.x, lane = tid & 63, wave = tid >> 6;
  const int lrow = lane & 15, quad = lane >> 4;
  const int srow = lane >> 3;
  const int scol = (((lane & 7) ^ srow) << 3);
  const int rsw = lrow & 7;
  const int pc[2] = { ((0 + quad) ^ rsw) << 3, ((4 + quad) ^ rsw) << 3 };

  // ===== P1: fc4 (jobs 0..2047) || lvl3 gates (jobs 2048..2559) =====
  for (int job = blockIdx.x; job < 2560; job += NBLK) {
    if (job < 2048) {
      uint16_t* As = smem;                 // 16 KB
      uint16_t* Bs = smem + 8192;          // 16 KB
      const int wm = (wave >> 1) * 64, wn = (wave & 1) * 64;
      long tm, tn;
      {
        int b = job;
        int x = b & 7, j = b >> 3, per = 64;       // nTm=512
        tn = j & 3; tm = (long)x * per + (j >> 2);
      }
      f32x4 acc[4][4] = {};
      for (int k0 = 0; k0 < 512; k0 += 64) {
#pragma unroll
        for (int j = 0; j < 4; ++j) {
          int grp = wave * 4 + j;
          int row = grp * 8 + srow;
          const uint16_t* gp = a.Cbf + (tm * 128 + row) * 512L + k0 + scol;
          __builtin_amdgcn_global_load_lds((gbl_void_t*)(uintptr_t)gp,
              (lds_void_t*)&As[grp * 512], 16, 0, 0);
        }
#pragma unroll
        for (int j = 0; j < 4; ++j) {
          int row = wave * 32 + j * 8 + srow;
          const uint16_t* gp = a.Wfc + (tn * BN + row) * 1024L + k0 + scol;
          __builtin_amdgcn_global_load_lds((gbl_void_t*)(uintptr_t)gp,
              (lds_void_t*)&Bs[(wave * 32 + j * 8) * 64], 16, 0, 0);
        }
        __syncthreads();
#pragma unroll
        for (int h = 0; h < 2; ++h) {
          bf16x8 av[4], bv[4];
#pragma unroll
          for (int f = 0; f < 4; ++f)
            av[f] = *(const bf16x8*)&As[(wm + f * 16 + lrow) * 64 + pc[h]];
#pragma unroll
          for (int f = 0; f < 4; ++f)
            bv[f] = *(const bf16x8*)&Bs[(wn + f * 16 + lrow) * 64 + pc[h]];
#pragma unroll
          for (int fm = 0; fm < 4; ++fm)
#pragma unroll
            for (int fn = 0; fn < 4; ++fn)
              acc[fm][fn] = __builtin_amdgcn_mfma_f32_16x16x32_bf16(
                  av[fm], bv[fn], acc[fm][fn], 0, 0, 0);
        }
        __syncthreads();
      }
#pragma unroll
      for (int fm = 0; fm < 4; ++fm) {
        long pg   = tm * 8 + (wm >> 4) + fm;
        long row0 = tm * 128 + wm + fm * 16 + quad * 4;
#pragma unroll
        for (int fn = 0; fn < 4; ++fn) {
          long col = tn * BN + wn + fn * 16 + lrow;
          float fx = a.FxAll[(273 + pg) * 512 + col] + a.bfb[col];
          float t = 0.f;
#pragma unroll
          for (int r = 0; r < 4; ++r)
            t += sig_(fx + acc[fm][fn][r]) *
                 bf2f(a.Cbf[(row0 + r) * 512 + col]);
          t += __shfl_xor(t, 16, 64);
          t += __shfl_xor(t, 32, 64);
          if (quad == 0) a.Fpart[pg * 512 + col] = t;
        }
      }
    } else {
      uint16_t* As = smem;                 // 8 KB
      uint16_t* Bs = smem + 4096;          // 24 KB
      const int wm = (wave >> 1) * 32, wn = (wave & 1) * 32;
      long tm, tn;
      {
        int b = job - 2048;
        int x = b & 7, j = b >> 3, per = 8;        // nTm=64
        tn = j & 7; tm = (long)x * per + (j >> 3);
      }
      f32x4 acc[3][2][2] = {};
      for (int k0 = 0; k0 < 1024; k0 += 64) {
#pragma unroll
        for (int j = 0; j < 2; ++j) {
          int grp = wave * 2 + j;
          int row = grp * 8 + srow;
          const uint16_t* gp = a.xhA + (tm * 64 + row) * 1024L + k0 + scol;
          __builtin_amdgcn_global_load_lds((gbl_void_t*)(uintptr_t)gp,
              (lds_void_t*)&As[grp * 512], 16, 0, 0);
        }
#pragma unroll
        for (int j = 0; j < 6; ++j) {
          int cc = wave * 6 + j;
          int g  = cc >> 3;
          long grow = (long)g * 512 + tn * 64 + (cc & 7) * 8 + srow;
          const uint16_t* gp = a.Wg + grow * 1024 + k0 + scol;
          __builtin_amdgcn_global_load_lds((gbl_void_t*)(uintptr_t)gp,
              (lds_void_t*)&Bs[cc * 512], 16, 0, 0);
        }
        __syncthreads();
#pragma unroll
        for (int h = 0; h < 2; ++h) {
          bf16x8 av[2];
#pragma unroll
          for (int f = 0; f < 2; ++f)
            av[f] = *(const bf16x8*)&As[(wm + f * 16 + lrow) * 64 + pc[h]];
#pragma unroll
          for (int g = 0; g < 3; ++g) {
            bf16x8 b0 = *(const bf16x8*)&Bs[(g * 64 + wn + lrow) * 64 +
                                            pc[h]];
            bf16x8 b1 = *(const bf16x8*)&Bs[(g * 64 + wn + 16 + lrow) * 64 +
                                            pc[h]];
#pragma unroll
            for (int fm = 0; fm < 2; ++fm) {
              acc[g][fm][0] = __builtin_amdgcn_mfma_f32_16x16x32_bf16(
                  av[fm], b0, acc[g][fm][0], 0, 0, 0);
              acc[g][fm][1] = __builtin_amdgcn_mfma_f32_16x16x32_bf16(
                  av[fm], b1, acc[g][fm][1], 0, 0, 0);
            }
          }
        }
        __syncthreads();
      }
#pragma unroll
      for (int fn = 0; fn < 2; ++fn) {
        long col = tn * 64 + wn + fn * 16 + lrow;
#pragma unroll
        for (int fm = 0; fm < 2; ++fm) {
          long row0 = tm * 64 + wm + fm * 16 + quad * 4;
#pragma unroll
          for (int r = 0; r < 4; ++r) {
            long row = row0 + r;
#pragma unroll
            for (int g = 0; g < 3; ++g)
              a.G3[row * 1536 + g * 512 + col] = acc[g][fm][fn][r];
          }
        }
      }
    }
  }
  gbar(a.bar);

  // ===== P2: lvl3 final (256 parents) =====
  if (blockIdx.x < 256 && tid < 128)
    level_final_body(blockIdx.x, tid, a.G3, a.Fpart, a.bi, a.bo, a.bu,
                     a.CbfU, a.Xbf + 17 * 512, a.xhB);
  gbar(a.bar);

  // ===== P3: fc2 (jobs 0..255) || lvl2 gates (jobs 256..287) =====
  if (blockIdx.x < 288) {
    int job = blockIdx.x;
    if (job < 256) {
      uint16_t* As = smem;                 // 8 KB
      uint16_t* Bs = smem + 4096;          // 16 KB
      const int wm = (wave >> 1) * 32, wn = (wave & 1) * 64;
      long tm, tn;
      {
        int b = job;
        int x = b & 7, j = b >> 3, per = 8;        // nTm=64
        tn = j & 3; tm = (long)x * per + (j >> 2);
      }
      f32x4 acc[2][4] = {};
      for (int k0 = 0; k0 < 512; k0 += 64) {
#pragma unroll
        for (int j = 0; j < 2; ++j) {
          int grp = wave * 2 + j;
          int row = grp * 8 + srow;
          const uint16_t* gp = a.CbfU + (tm * 64 + row) * 512L + k0 + scol;
          __builtin_amdgcn_global_load_lds((gbl_void_t*)(uintptr_t)gp,
              (lds_void_t*)&As[grp * 512], 16, 0, 0);
        }
#pragma unroll
        for (int j = 0; j < 4; ++j) {
          int row = wave * 32 + j * 8 + srow;
          const uint16_t* gp = a.Wfc + (tn * BN + row) * 1024L + k0 + scol;
          __builtin_amdgcn_global_load_lds((gbl_void_t*)(uintptr_t)gp,
              (lds_void_t*)&Bs[(wave * 32 + j * 8) * 64], 16, 0, 0);
        }
        __syncthreads();
#pragma unroll
        for (int h = 0; h < 2; ++h) {
          bf16x8 av[2], bv[4];
#pragma unroll
          for (int f = 0; f < 2; ++f)
            av[f] = *(const bf16x8*)&As[(wm + f * 16 + lrow) * 64 + pc[h]];
#pragma unroll
          for (int f = 0; f < 4; ++f)
            bv[f] = *(const bf16x8*)&Bs[(wn + f * 16 + lrow) * 64 + pc[h]];
#pragma unroll
          for (int fm = 0; fm < 2; ++fm)
#pragma unroll
            for (int fn = 0; fn < 4; ++fn)
              acc[fm][fn] = __builtin_amdgcn_mfma_f32_16x16x32_bf16(
                  av[fm], bv[fn], acc[fm][fn], 0, 0, 0);
        }
        __syncthreads();
      }
#pragma unroll
      for (int fm = 0; fm < 2; ++fm) {
        long pg   = tm * 4 + (wm >> 4) + fm;
        long row0 = tm * 64 + wm + fm * 16 + quad * 4;
#pragma unroll
        for (int fn = 0; fn < 4; ++fn) {
          long col = tn * BN + wn + fn * 16 + lrow;
          float fx = a.FxAll[(17 + pg) * 512 + col] + a.bfb[col];
          float t = 0.f;
#pragma unroll
          for (int r = 0; r < 4; ++r)
            t += sig_(fx + acc[fm][fn][r]) *
                 bf2f(a.CbfU[(row0 + r) * 512 + col]);
          t += __shfl_xor(t, 16, 64);
          t += __shfl_xor(t, 32, 64);
          if (quad == 0) a.Fpart[pg * 512 + col] = t;
        }
      }
    } else {
      uint16_t* As = smem;                 // 8 KB
      uint16_t* Bs = smem + 4096;          // 24 KB
      const int wm = (wave >> 1) * 32, wn = (wave & 1) * 32;
      int b = job - 256;
      long tm = b >> 3, tn = b & 7;
      f32x4 acc[3][2][2] = {};
      for (int k0 = 0; k0 < 1024; k0 += 64) {
#pragma unroll
        for (int j = 0; j < 2; ++j) {
          int grp = wave * 2 + j;
          int row = grp * 8 + srow;
          const uint16_t* gp = a.xhB + (tm * 64 + row) * 1024L + k0 + scol;
          __builtin_amdgcn_global_load_lds((gbl_void_t*)(uintptr_t)gp,
              (lds_void_t*)&As[grp * 512], 16, 0, 0);
        }
#pragma unroll
        for (int j = 0; j < 6; ++j) {
          int cc = wave * 6 + j;
          int g  = cc >> 3;
          long grow = (long)g * 512 + tn * 64 + (cc & 7) * 8 + srow;
          const uint16_t* gp = a.Wg + grow * 1024 + k0 + scol;
          __builtin_amdgcn_global_load_lds((gbl_void_t*)(uintptr_t)gp,
              (lds_void_t*)&Bs[cc * 512], 16, 0, 0);
        }
        __syncthreads();
#pragma unroll
        for (int h = 0; h < 2; ++h) {
          bf16x8 av[2];
#pragma unroll
          for (int f = 0; f < 2; ++f)
            av[f] = *(const bf16x8*)&As[(wm + f * 16 + lrow) * 64 + pc[h]];
#pragma unroll
          for (int g = 0; g < 3; ++g) {
            bf16x8 b0 = *(const bf16x8*)&Bs[(g * 64 + wn + lrow) * 64 +
                                            pc[h]];
            bf16x8 b1 = *(const bf16x8*)&Bs[(g * 64 + wn + 16 + lrow) * 64 +
                                            pc[h]];
#pragma unroll
            for (int fm = 0; fm < 2; ++fm) {
              acc[g][fm][0] = __builtin_amdgcn_mfma_f32_16x16x32_bf16(
                  av[fm], b0, acc[g][fm][0], 0, 0, 0);
              acc[g][fm][1] = __builtin_amdgcn_mfma_f32_16x16x32_bf16(
                  av[fm], b1, acc[g][fm][1], 0, 0, 0);
            }
          }
        }
        __syncthreads();
      }
#pragma unroll
      for (int fn = 0; fn < 2; ++fn) {
        long col = tn * 64 + wn + fn * 16 + lrow;
#pragma unroll
        for (int fm = 0; fm < 2; ++fm) {
          long row0 = tm * 64 + wm + fm * 16 + quad * 4;
#pragma unroll
          for (int r = 0; r < 4; ++r) {
            long row = row0 + r;
#pragma unroll
            for (int g = 0; g < 3; ++g)
              a.G3[row * 1536 + g * 512 + col] = acc[g][fm][fn][r];
          }
        }
      }
    }
  }
  gbar(a.bar);

  // ===== P4: lvl2 final (16 parents) =====
  if (blockIdx.x < 16 && tid < 128)
    level_final_body(blockIdx.x, tid, a.G3, a.Fpart, a.bi, a.bo, a.bu,
                     a.CbfU2, a.Xbf + 1 * 512, a.xhC);
  gbar(a.bar);

  // ===== P5: lvl2 fc (jobs 0..15) || lvl1 gate dots (jobs 16..6159) =====
  for (int job = blockIdx.x; job < 6160; job += NBLK) {
    if (job < 16) {
      uint16_t* As = smem;                 // 8 KB
      uint16_t* Bs = smem + 4096;          // 16 KB
      const int wm = (wave >> 1) * 32, wn = (wave & 1) * 64;
      long tm = job >> 2, tn = job & 3;    // nTm=4 plain map
      f32x4 acc[2][4] = {};
      for (int k0 = 0; k0 < 512; k0 += 64) {
#pragma unroll
        for (int j = 0; j < 2; ++j) {
          int grp = wave * 2 + j;
          int row = grp * 8 + srow;
          const uint16_t* gp = a.CbfU2 + (tm * 64 + row) * 512L + k0 + scol;
          __builtin_amdgcn_global_load_lds((gbl_void_t*)(uintptr_t)gp,
              (lds_void_t*)&As[grp * 512], 16, 0, 0);
        }
#pragma unroll
        for (int j = 0; j < 4; ++j) {
          int row = wave * 32 + j * 8 + srow;
          const uint16_t* gp = a.Wfc + (tn * 128 + row) * 1024L + k0 + scol;
          __builtin_amdgcn_global_load_lds((gbl_void_t*)(uintptr_t)gp,
              (lds_void_t*)&Bs[(wave * 32 + j * 8) * 64], 16, 0, 0);
        }
        __syncthreads();
#pragma unroll
        for (int h = 0; h < 2; ++h) {
          bf16x8 av[2], bv[4];
#pragma unroll
          for (int f = 0; f < 2; ++f)
            av[f] = *(const bf16x8*)&As[(wm + f * 16 + lrow) * 64 + pc[h]];
#pragma unroll
          for (int f = 0; f < 4; ++f)
            bv[f] = *(const bf16x8*)&Bs[(wn + f * 16 + lrow) * 64 + pc[h]];
#pragma unroll
          for (int fm = 0; fm < 2; ++fm)
#pragma unroll
            for (int fn = 0; fn < 4; ++fn)
              acc[fm][fn] = __builtin_amdgcn_mfma_f32_16x16x32_bf16(
                  av[fm], bv[fn], acc[fm][fn], 0, 0, 0);
        }
        __syncthreads();
      }
#pragma unroll
      for (int fm = 0; fm < 2; ++fm) {
        long pg   = tm * 4 + (wm >> 4) + fm;
        long row0 = tm * 64 + wm + fm * 16 + quad * 4;
#pragma unroll
        for (int fn = 0; fn < 4; ++fn) {
          long col = tn * 128 + wn + fn * 16 + lrow;
          float fx = a.FxAll[(1 + pg) * 512 + col] + a.bfb[col];
          float t = 0.f;
#pragma unroll
          for (int r = 0; r < 4; ++r)
            t += sig_(fx + acc[fm][fn][r]) *
                 bf2f(a.CbfU2[(row0 + r) * 512 + col]);
          t += __shfl_xor(t, 16, 64);
          t += __shfl_xor(t, 32, 64);
          if (quad == 0) a.Fpart[pg * 512 + col] = t;
        }
      }
    } else {
      int wid = (job - 16) * 4 + wave;     // 0..24575
      int m = wid / 1536, n = wid - m * 1536;
      const uint16_t* ap = a.xhC + (long)m * 1024;
      const uint16_t* bp = a.Wg + (long)n * 1024;
      int k0 = lane * 16;
      float s = 0.f;
#pragma unroll
      for (int j = 0; j < 16; j += 4) {
        ushort4 avv = *(const ushort4*)(ap + k0 + j);
        ushort4 bvv = *(const ushort4*)(bp + k0 + j);
        s += bf2f(avv.x) * bf2f(bvv.x) + bf2f(avv.y) * bf2f(bvv.y)
           + bf2f(avv.z) * bf2f(bvv.z) + bf2f(avv.w) * bf2f(bvv.w);
      }
#pragma unroll
      for (int off = 32; off; off >>= 1) s += __shfl_xor(s, off, 64);
      if (lane == 0) a.Gf[(long)m * 1536 + n] = s;
    }
  }
  gbar(a.bar);

  // ===== P6: lvl1 tail (block 0 only; 256 thr, 8 iters) =====
  if (blockIdx.x == 0) {
    float* Hl = (float*)smem_raw;                        // 32 KB
    for (int it = 0; it < 8; ++it) {
      int idx = it * 256 + tid;                          // 0..2047
      int p = idx >> 7, hq = (idx & 127) << 2;
      const float* g = a.Gf + (long)p * 1536;
      float4 gi = *(const float4*)(g + hq);
      float4 go = *(const float4*)(g + 512 + hq);
      float4 gu = *(const float4*)(g + 1024 + hq);
      float4 b_i = *(const float4*)(a.bi + hq);
      float4 b_o = *(const float4*)(a.bo + hq);
      float4 b_u = *(const float4*)(a.bu + hq);
      float4 fp = *(const float4*)(a.Fpart + (long)p * 512 + hq);
      const float* gip = &gi.x; const float* gop = &go.x;
      const float* gup = &gu.x; const float* bip = &b_i.x;
      const float* bop = &b_o.x; const float* bup = &b_u.x;
      const float* fpp = &fp.x;
      float4 hv, cv;
      float* hvp = &hv.x; float* cvp = &cv.x;
#pragma unroll
      for (int j = 0; j < 4; ++j) {
        float iv = sig_(gip[j] + bip[j]);
        float ov = sig_(gop[j] + bop[j]);
        float uv = tanh_(gup[j] + bup[j]);
        float c  = iv * uv + fpp[j];
        cvp[j] = c;
        hvp[j] = ov * tanh_(c);
      }
      *(float4*)(a.CupA + (long)p * 512 + hq) = cv;
      *(float4*)(&Hl[p * 512 + hq]) = hv;
    }
    __syncthreads();
    if (tid < 128) {
      int hq = tid << 2;
      float4 s = {0.f, 0.f, 0.f, 0.f};
#pragma unroll
      for (int b = 0; b < 16; ++b) {
        float4 v = *(const float4*)(&Hl[b * 512 + hq]);
        s.x += v.x; s.y += v.y; s.z += v.z; s.w += v.w;
      }
      *(ushort4*)(a.xhC + hq) = *(const ushort4*)(a.Xbf + hq);
      ushort4 hw = {f2bf(s.x), f2bf(s.y), f2bf(s.z), f2bf(s.w)};
      *(ushort4*)(a.xhC + 512 + hq) = hw;
    }
  }
  gbar(a.bar);

  // ===== P7: root dots (2432 block-jobs: gates wid<1536, Fc wid>=1536) =====
  for (int bj = blockIdx.x; bj < 2432; bj += NBLK) {
    int wid = bj * 4 + wave;                             // 0..9727
    if (wid < 1536) {
      const uint16_t* ap = a.xhC;
      const uint16_t* bp = a.Wg + (long)wid * 1024;
      int k0 = lane * 16;
      float s = 0.f;
#pragma unroll
      for (int j = 0; j < 16; j += 4) {
        ushort4 avv = *(const ushort4*)(ap + k0 + j);
        ushort4 bvv = *(const ushort4*)(bp + k0 + j);
        s += bf2f(avv.x) * bf2f(bvv.x) + bf2f(avv.y) * bf2f(bvv.y)
           + bf2f(avv.z) * bf2f(bvv.z) + bf2f(avv.w) * bf2f(bvv.w);
      }
#pragma unroll
      for (int off = 32; off; off >>= 1) s += __shfl_xor(s, off, 64);
      if (lane == 0) a.Gf[wid] = s;
    } else {
      int w2 = wid - 1536;                               // 0..8191
      int m = w2 >> 9, n = w2 & 511;
      const float* ap = a.CupA + (long)m * 512;
      const float* bp = a.WfF + (long)n * 1024;
      int k0 = lane * 8;
      float s = 0.f;
#pragma unroll
      for (int j = 0; j < 8; j += 4) {
        float4 avv = *(const float4*)(ap + k0 + j);
        float4 bvv = *(const float4*)(bp + k0 + j);
        s += avv.x * bvv.x + avv.y * bvv.y + avv.z * bvv.z + avv.w * bvv.w;
      }
#pragma unroll
      for (int off = 32; off; off >>= 1) s += __shfl_xor(s, off, 64);
      if (lane == 0) a.Fc[(long)m * 512 + n] = s;
    }
  }
  gbar(a.bar);

  // ===== P8: root tail (block 0, 128 thr) =====
  if (blockIdx.x == 0 && tid < 128) {
    int hq = tid << 2;
    float4 fxv = *(const float4*)(a.FxAll + hq);
    float4 bfv = *(const float4*)(a.bfb + hq);
    float fx0 = fxv.x + bfv.x, fx1 = fxv.y + bfv.y;
    float fx2 = fxv.z + bfv.z, fx3 = fxv.w + bfv.w;
    float a0 = 0.f, a1 = 0.f, a2 = 0.f, a3 = 0.f;
#pragma unroll 4
    for (int b = 0; b < 16; ++b) {
      float4 f = *(const float4*)(a.Fc + (long)b * 512 + hq);
      float4 c = *(const float4*)(a.CupA + (long)b * 512 + hq);
      a0 += sig_(fx0 + f.x) * c.x;
      a1 += sig_(fx1 + f.y) * c.y;
      a2 += sig_(fx2 + f.z) * c.z;
      a3 += sig_(fx3 + f.w) * c.w;
    }
    float fpp[4] = {a0, a1, a2, a3};
    float4 gi = *(const float4*)(a.Gf + hq);
    float4 go = *(const float4*)(a.Gf + 512 + hq);
    float4 gu = *(const float4*)(a.Gf + 1024 + hq);
    float4 b_i = *(const float4*)(a.bi + hq);
    float4 b_o = *(const float4*)(a.bo + hq);
    float4 b_u = *(const float4*)(a.bu + hq);
    const float* gip = &gi.x; const float* gop = &go.x;
    const float* gup = &gu.x; const float* bip = &b_i.x;
    const float* bop = &b_o.x; const float* bup = &b_u.x;
    float4 hv, cv;
    float* hvp = &hv.x; float* cvp = &cv.x;
#pragma unroll
    for (int j = 0; j < 4; ++j) {
      float iv = sig_(gip[j] + bip[j]);
      float ov = sig_(gop[j] + bop[j]);
      float uv = tanh_(gup[j] + bup[j]);
      float c  = iv * uv + fpp[j];
      cvp[j] = c;
      hvp[j] = ov * tanh_(c);
    }
    *(float4*)(a.H  + hq) = hv;
    *(float4*)(a.Cv + hq) = cv;
  }
}

// ---------------------------------------------------------------------------
extern "C" void kernel_launch(void* const* d_in, const int* in_sizes, int n_in,
                              void* d_out, int out_size, void* d_ws, size_t ws_size,
                              hipStream_t stream) {
  const float* x    = (const float*)d_in[0];
  const float* wi_w = (const float*)d_in[1];
  const float* wi_b = (const float*)d_in[2];
  const float* wf_w = (const float*)d_in[3];
  const float* wf_b = (const float*)d_in[4];
  const float* wo_w = (const float*)d_in[5];
  const float* wo_b = (const float*)d_in[6];
  const float* wu_w = (const float*)d_in[7];
  const float* wu_b = (const float*)d_in[8];
  (void)in_sizes; (void)n_in; (void)out_size; (void)ws_size;

  static const long offs[5] = {0, 1, 17, 273, 4369};
  const long NTOT = 69905;

  // ---- workspace ----
  char* ws = (char*)d_ws;
  size_t off = 0;
  auto alloc = [&](size_t bytes) -> void* {
    void* p = ws + off;
    off += (bytes + 255) & ~(size_t)255;
    return p;
  };
  uint16_t* Xbf   = (uint16_t*)alloc(NTOT * 512 * 2);
  uint16_t* Wgw   = (uint16_t*)alloc((size_t)2048 * 1024 * 2);
  uint16_t* Wg    = Wgw;
  uint16_t* Wf    = Wgw + (size_t)1536 * 1024;
  float*    FxAll = (float*)alloc((size_t)4480 * 512 * 4);
  uint16_t* Cbf   = (uint16_t*)alloc((size_t)65536 * 512 * 2);
  uint16_t* CbfU  = (uint16_t*)alloc((size_t)4096 * 512 * 2);
  uint16_t* CbfU2 = (uint16_t*)alloc((size_t)256 * 512 * 2);
  uint16_t* xhA   = (uint16_t*)alloc((size_t)4096 * 1024 * 2);
  uint16_t* xhB   = (uint16_t*)alloc((size_t)256 * 1024 * 2);
  uint16_t* xhC   = (uint16_t*)alloc((size_t)16 * 1024 * 2);
  float*    Fpart = (float*)alloc((size_t)4096 * 512 * 4);
  float*    G3    = (float*)alloc((size_t)4096 * 1536 * 4);
  float*    Gf    = (float*)alloc((size_t)16 * 1536 * 4);
  float*    Fc    = (float*)alloc((size_t)16 * 512 * 4);
  float*    CupA  = (float*)alloc((size_t)16 * 512 * 4);
  unsigned* bar   = (unsigned*)alloc(256);

  // barrier init (captured; runs each replay)
  hipMemsetAsync(bar, 0, 2 * sizeof(unsigned), stream);

  // ---- merged convert: all x + 4 weight matrices ----
  {
    long n4x = NTOT * 512 / 4;
    k_conv_all<<<8192, 256, 0, stream>>>(
        (const float4*)x, (ushort4*)Xbf, n4x,
        (const float4*)wi_w, (const float4*)wo_w,
        (const float4*)wu_w, (const float4*)wf_w, (ushort4*)Wgw);
  }

  // ---- leaf level + FxAll gemm in ONE launch (4096 + 140 blocks) ----
  k_leaf_fx<<<4236, 256, 0, stream>>>(
      Xbf + offs[4] * 512, Wg, wi_b, wo_b, wu_b,
      Cbf, Xbf + offs[3] * 512, xhA,
      Xbf, Wf, FxAll);

  // ---- everything else: ONE persistent kernel, 768 blocks, 7 barriers ----
  CoopArgs ca;
  ca.Cbf = Cbf; ca.Wfc = Wf + 512; ca.FxAll = FxAll; ca.bfb = wf_b;
  ca.Fpart = Fpart; ca.xhA = xhA; ca.Wg = Wg; ca.G3 = G3;
  ca.bi = wi_b; ca.bo = wo_b; ca.bu = wu_b;
  ca.CbfU = CbfU; ca.Xbf = Xbf; ca.xhB = xhB; ca.CbfU2 = CbfU2;
  ca.xhC = xhC; ca.Gf = Gf; ca.CupA = CupA; ca.WfF = wf_w + 512;
  ca.Fc = Fc; ca.H = (float*)d_out; ca.Cv = (float*)d_out + 512;
  ca.bar = bar;
  k_coop<<<NBLK, 256, 0, stream>>>(ca);
}

// Round 11
// 481.403 us; speedup vs baseline: 3.2444x; 3.2444x over previous
//
#include <hip/hip_runtime.h>
#include <stdint.h>
#include <stddef.h>

// ---------------------------------------------------------------------------
// CSTreeLSTM on gfx950. Levels 1,16,256,4096,65536 (x offsets 0,1,17,273,4369).
// Round 19: revert to round-17 (best measured, 464.8us). Round-18's
// persistent-kernel tail is dead: 7 software grid barriers cost ~150us each
// (768 spinners cross-XCD polling one L2 line). Chain: conv -> leaf_fx ->
// fc4||l3gates -> final3 -> fc2||l2gates -> final2 -> fcdot -> lvl1_tail ->
// dot_merge -> root_tail. All bodies r17-verbatim.
// ---------------------------------------------------------------------------

typedef __bf16 bf16x8 __attribute__((ext_vector_type(8)));
typedef float  f32x4  __attribute__((ext_vector_type(4)));
typedef void __attribute__((address_space(3))) lds_void_t;
typedef void __attribute__((address_space(1))) gbl_void_t;

__device__ __forceinline__ uint16_t f2bf(float f) {
  union { __bf16 b; uint16_t u; } v;
  v.b = (__bf16)f;              // RTNE, compiler emits v_cvt_pk_bf16_f32
  return v.u;
}
__device__ __forceinline__ float bf2f(uint16_t u) {
  union { uint32_t u; float f; } v; v.u = (uint32_t)u << 16;
  return v.f;
}
// native v_rcp_f32 (~1 ulp) -- error budget is huge
__device__ __forceinline__ float sig_(float x) {
  return __builtin_amdgcn_rcpf(1.0f + __expf(-x));
}
// tanh(x) = 2/(1+exp(-2x)) - 1 : mul+exp+add+rcp+fma, no clamp, inf-safe
__device__ __forceinline__ float tanh_(float x) {
  return __builtin_fmaf(2.f,
      __builtin_amdgcn_rcpf(1.f + __expf(-2.f * x)), -1.f);
}

// ---- merged convert: all x rows + 4 weight matrices ------------------------
__global__ void k_conv_all(const float4* __restrict__ x,
                           ushort4* __restrict__ xdst, long n4x,
                           const float4* __restrict__ w0,
                           const float4* __restrict__ w1,
                           const float4* __restrict__ w2,
                           const float4* __restrict__ w3,
                           ushort4* __restrict__ wdst) {
  const long per4 = (long)512 * 1024 / 4;
  const long total = n4x + 4 * per4;
  long i = blockIdx.x * (long)blockDim.x + threadIdx.x;
  long stride = (long)gridDim.x * blockDim.x;
  for (; i < total; i += stride) {
    float4 v;
    ushort4* d;
    if (i < n4x) {
      v = x[i];
      d = xdst + i;
    } else {
      long j = i - n4x;
      long seg = j / per4, off2 = j - seg * per4;
      const float4* s = (seg == 0) ? w0 : (seg == 1) ? w1
                       : (seg == 2) ? w2 : w3;
      v = s[off2];
      d = wdst + j;
    }
    ushort4 r;
    r.x = f2bf(v.x); r.y = f2bf(v.y); r.z = f2bf(v.z); r.w = f2bf(v.w);
    *d = r;
  }
}

#define BM 128
#define BN 128
#define BK 32

// ---- merged leaf k_level + FxAll gemm_bt -----------------------------------
__global__ __launch_bounds__(256, 3)
void k_leaf_fx(const uint16_t* __restrict__ Xleaf,       // Xbf + offs4*512
               const uint16_t* __restrict__ Wg,
               const float* __restrict__ bi, const float* __restrict__ bo,
               const float* __restrict__ bu,
               uint16_t* __restrict__ Cbf,
               const uint16_t* __restrict__ Xnext,       // Xbf + offs3*512
               uint16_t* __restrict__ xh_next,           // xhA
               const uint16_t* __restrict__ Xbf,         // for FxAll A
               const uint16_t* __restrict__ Wf,          // FxAll B
               float* __restrict__ FxAll) {
  __shared__ uint16_t smem[20480];                       // 40 KB pool
  const int tid = threadIdx.x, lane = tid & 63, wave = tid >> 6;
  const int lrow = lane & 15, quad = lane >> 4;

  if (blockIdx.x < 4096) {
    uint16_t* As = smem;
    uint16_t* Bs = smem + 8192;
    const int wm = (wave >> 1) * 64, wn = (wave & 1) * 32;
    long tm, tn;
    {
      int b = blockIdx.x;
      int x = b & 7, j = b >> 3, per = 64;       // nTm=512
      tn = j & 7; tm = (long)x * per + (j >> 3);
    }
    f32x4 acc[3][4][2] = {};
    const int srow = lane >> 3;
    const int scol = (((lane & 7) ^ srow) << 3);
    const int rsw = lrow & 7;
    const int pc[2] = { ((0 + quad) ^ rsw) << 3, ((4 + quad) ^ rsw) << 3 };

    for (int k0 = 0; k0 < 512; k0 += 64) {
#pragma unroll
      for (int j = 0; j < 4; ++j) {
        int grp = wave * 4 + j;
        int row = grp * 8 + srow;
        const uint16_t* gp = Xleaf + (tm * 128 + row) * 512L + k0 + scol;
        __builtin_amdgcn_global_load_lds((gbl_void_t*)(uintptr_t)gp,
            (lds_void_t*)&As[grp * 512], 16, 0, 0);
      }
#pragma unroll
      for (int j = 0; j < 6; ++j) {
        int cc = wave * 6 + j;
        int g  = cc >> 3;
        long grow = (long)g * 512 + tn * 64 + (cc & 7) * 8 + srow;
        const uint16_t* gp = Wg + grow * 1024 + k0 + scol;
        __builtin_amdgcn_global_load_lds((gbl_void_t*)(uintptr_t)gp,
            (lds_void_t*)&Bs[cc * 512], 16, 0, 0);
      }
      __syncthreads();
#pragma unroll
      for (int h = 0; h < 2; ++h) {
        bf16x8 a[4];
#pragma unroll
        for (int f = 0; f < 4; ++f)
          a[f] = *(const bf16x8*)&As[(wm + f * 16 + lrow) * 64 + pc[h]];
#pragma unroll
        for (int g = 0; g < 3; ++g) {
          bf16x8 b0 = *(const bf16x8*)&Bs[(g * 64 + wn + lrow) * 64 + pc[h]];
          bf16x8 b1 = *(const bf16x8*)&Bs[(g * 64 + wn + 16 + lrow) * 64 +
                                          pc[h]];
#pragma unroll
          for (int fm = 0; fm < 4; ++fm) {
            acc[g][fm][0] = __builtin_amdgcn_mfma_f32_16x16x32_bf16(
                a[fm], b0, acc[g][fm][0], 0, 0, 0);
            acc[g][fm][1] = __builtin_amdgcn_mfma_f32_16x16x32_bf16(
                a[fm], b1, acc[g][fm][1], 0, 0, 0);
          }
        }
      }
      __syncthreads();
    }
#pragma unroll
    for (int fn = 0; fn < 2; ++fn) {
      long col = tn * 64 + wn + fn * 16 + lrow;
      float biv = bi[col], bov = bo[col], buv = bu[col];
#pragma unroll
      for (int fm = 0; fm < 4; ++fm) {
        long row0 = tm * 128 + wm + fm * 16 + quad * 4;
        long pg   = tm * 8 + (wm >> 4) + fm;
        float hs = 0.f;
#pragma unroll
        for (int r = 0; r < 4; ++r) {
          long row = row0 + r;
          float iv = sig_(acc[0][fm][fn][r] + biv);
          float ov = sig_(acc[1][fm][fn][r] + bov);
          float uv = tanh_(acc[2][fm][fn][r] + buv);
          float c  = iv * uv;
          Cbf[row * 512 + col] = f2bf(c);
          hs += ov * tanh_(c);
        }
        hs += __shfl_xor(hs, 16, 64);
        hs += __shfl_xor(hs, 32, 64);
        if (quad == 0) {
          xh_next[pg * 1024 + col]       = Xnext[pg * 512 + col];
          xh_next[pg * 1024 + 512 + col] = f2bf(hs);
        }
      }
    }
  } else {
    uint16_t* As = smem;
    uint16_t* Bs = smem + 4096;
    const int wm = (wave >> 1) * 64, wn = (wave & 1) * 64;
    int bid2 = (int)blockIdx.x - 4096;
    const long tm = bid2 % 35, tn = bid2 / 35;
    f32x4 acc[4][4] = {};
    const int srow2 = lane >> 2, scol2 = (lane & 3) * 8;
    for (int k0 = 0; k0 < 512; k0 += BK) {
#pragma unroll
      for (int i = 0; i < 2; ++i) {
        int row = i * 64 + wave * 16 + srow2;
        const uint16_t* gp = Xbf + (tm * BM + row) * 512L + k0 + scol2;
        __builtin_amdgcn_global_load_lds((gbl_void_t*)(uintptr_t)gp,
            (lds_void_t*)&As[i * 2048 + wave * 512], 16, 0, 0);
      }
#pragma unroll
      for (int i = 0; i < 2; ++i) {
        int row = i * 64 + wave * 16 + srow2;
        const uint16_t* gp = Wf + (tn * BN + row) * 1024L + k0 + scol2;
        __builtin_amdgcn_global_load_lds((gbl_void_t*)(uintptr_t)gp,
            (lds_void_t*)&Bs[i * 2048 + wave * 512], 16, 0, 0);
      }
      __syncthreads();
      bf16x8 a[4], b[4];
#pragma unroll
      for (int f = 0; f < 4; ++f)
        a[f] = *(const bf16x8*)&As[(wm + f * 16 + lrow) * BK + quad * 8];
#pragma unroll
      for (int f = 0; f < 4; ++f)
        b[f] = *(const bf16x8*)&Bs[(wn + f * 16 + lrow) * BK + quad * 8];
#pragma unroll
      for (int fm = 0; fm < 4; ++fm)
#pragma unroll
        for (int fn = 0; fn < 4; ++fn)
          acc[fm][fn] = __builtin_amdgcn_mfma_f32_16x16x32_bf16(
              a[fm], b[fn], acc[fm][fn], 0, 0, 0);
      __syncthreads();
    }
#pragma unroll
    for (int fm = 0; fm < 4; ++fm)
#pragma unroll
      for (int fn = 0; fn < 4; ++fn) {
        long col  = tn * BN + wn + fn * 16 + lrow;
        long row0 = tm * BM + wm + fm * 16 + quad * 4;
#pragma unroll
        for (int r = 0; r < 4; ++r)
          FxAll[(row0 + r) * 512 + col] = acc[fm][fn][r];
      }
  }
}

// ---- merged: leaf fc_combine (2048 blks) || lvl3 gates GEMM (512 blks) -----
__global__ __launch_bounds__(256, 3)
void k_fc4_l3g(const uint16_t* __restrict__ Cbf,         // leaf C (fc A)
               const uint16_t* __restrict__ Wfc,         // Wf+512, ldb 1024
               const float* __restrict__ Fx,             // FxAll+offs3*512
               const float* __restrict__ bfb,
               float* __restrict__ Fpart,
               const uint16_t* __restrict__ xhA,         // lvl3 A, lda 1024
               const uint16_t* __restrict__ Wg,
               float* __restrict__ G3) {
  __shared__ uint16_t smem[16384];                       // 32 KB pool
  const int tid = threadIdx.x, lane = tid & 63, wave = tid >> 6;
  const int lrow = lane & 15, quad = lane >> 4;
  const int srow = lane >> 3;
  const int scol = (((lane & 7) ^ srow) << 3);
  const int rsw = lrow & 7;
  const int pc[2] = { ((0 + quad) ^ rsw) << 3, ((4 + quad) ^ rsw) << 3 };

  if (blockIdx.x < 2048) {
    uint16_t* As = smem;                 // 16 KB
    uint16_t* Bs = smem + 8192;          // 16 KB
    const int wm = (wave >> 1) * 64, wn = (wave & 1) * 64;
    long tm, tn;
    {
      int b = blockIdx.x;
      int x = b & 7, j = b >> 3, per = 64;       // nTm=512
      tn = j & 3; tm = (long)x * per + (j >> 2);
    }
    f32x4 acc[4][4] = {};
    for (int k0 = 0; k0 < 512; k0 += 64) {
#pragma unroll
      for (int j = 0; j < 4; ++j) {
        int grp = wave * 4 + j;
        int row = grp * 8 + srow;
        const uint16_t* gp = Cbf + (tm * 128 + row) * 512L + k0 + scol;
        __builtin_amdgcn_global_load_lds((gbl_void_t*)(uintptr_t)gp,
            (lds_void_t*)&As[grp * 512], 16, 0, 0);
      }
#pragma unroll
      for (int j = 0; j < 4; ++j) {
        int row = wave * 32 + j * 8 + srow;
        const uint16_t* gp = Wfc + (tn * BN + row) * 1024L + k0 + scol;
        __builtin_amdgcn_global_load_lds((gbl_void_t*)(uintptr_t)gp,
            (lds_void_t*)&Bs[(wave * 32 + j * 8) * 64], 16, 0, 0);
      }
      __syncthreads();
#pragma unroll
      for (int h = 0; h < 2; ++h) {
        bf16x8 a[4], b[4];
#pragma unroll
        for (int f = 0; f < 4; ++f)
          a[f] = *(const bf16x8*)&As[(wm + f * 16 + lrow) * 64 + pc[h]];
#pragma unroll
        for (int f = 0; f < 4; ++f)
          b[f] = *(const bf16x8*)&Bs[(wn + f * 16 + lrow) * 64 + pc[h]];
#pragma unroll
        for (int fm = 0; fm < 4; ++fm)
#pragma unroll
          for (int fn = 0; fn < 4; ++fn)
            acc[fm][fn] = __builtin_amdgcn_mfma_f32_16x16x32_bf16(
                a[fm], b[fn], acc[fm][fn], 0, 0, 0);
      }
      __syncthreads();
    }
#pragma unroll
    for (int fm = 0; fm < 4; ++fm) {
      long pg   = tm * 8 + (wm >> 4) + fm;
      long row0 = tm * 128 + wm + fm * 16 + quad * 4;
#pragma unroll
      for (int fn = 0; fn < 4; ++fn) {
        long col = tn * BN + wn + fn * 16 + lrow;
        float fx = Fx[pg * 512 + col] + bfb[col];
        float t = 0.f;
#pragma unroll
        for (int r = 0; r < 4; ++r)
          t += sig_(fx + acc[fm][fn][r]) * bf2f(Cbf[(row0 + r) * 512 + col]);
        t += __shfl_xor(t, 16, 64);
        t += __shfl_xor(t, 32, 64);
        if (quad == 0) Fpart[pg * 512 + col] = t;
      }
    }
  } else {
    uint16_t* As = smem;                 // 8 KB
    uint16_t* Bs = smem + 4096;          // 24 KB
    const int wm = (wave >> 1) * 32, wn = (wave & 1) * 32;
    long tm, tn;
    {
      int b = (int)blockIdx.x - 2048;
      int x = b & 7, j = b >> 3, per = 8;        // nTm=64
      tn = j & 7; tm = (long)x * per + (j >> 3);
    }
    f32x4 acc[3][2][2] = {};
    for (int k0 = 0; k0 < 1024; k0 += 64) {
#pragma unroll
      for (int j = 0; j < 2; ++j) {
        int grp = wave * 2 + j;
        int row = grp * 8 + srow;
        const uint16_t* gp = xhA + (tm * 64 + row) * 1024L + k0 + scol;
        __builtin_amdgcn_global_load_lds((gbl_void_t*)(uintptr_t)gp,
            (lds_void_t*)&As[grp * 512], 16, 0, 0);
      }
#pragma unroll
      for (int j = 0; j < 6; ++j) {
        int cc = wave * 6 + j;
        int g  = cc >> 3;
        long grow = (long)g * 512 + tn * 64 + (cc & 7) * 8 + srow;
        const uint16_t* gp = Wg + grow * 1024 + k0 + scol;
        __builtin_amdgcn_global_load_lds((gbl_void_t*)(uintptr_t)gp,
            (lds_void_t*)&Bs[cc * 512], 16, 0, 0);
      }
      __syncthreads();
#pragma unroll
      for (int h = 0; h < 2; ++h) {
        bf16x8 a[2];
#pragma unroll
        for (int f = 0; f < 2; ++f)
          a[f] = *(const bf16x8*)&As[(wm + f * 16 + lrow) * 64 + pc[h]];
#pragma unroll
        for (int g = 0; g < 3; ++g) {
          bf16x8 b0 = *(const bf16x8*)&Bs[(g * 64 + wn + lrow) * 64 + pc[h]];
          bf16x8 b1 = *(const bf16x8*)&Bs[(g * 64 + wn + 16 + lrow) * 64 +
                                          pc[h]];
#pragma unroll
          for (int fm = 0; fm < 2; ++fm) {
            acc[g][fm][0] = __builtin_amdgcn_mfma_f32_16x16x32_bf16(
                a[fm], b0, acc[g][fm][0], 0, 0, 0);
            acc[g][fm][1] = __builtin_amdgcn_mfma_f32_16x16x32_bf16(
                a[fm], b1, acc[g][fm][1], 0, 0, 0);
          }
        }
      }
      __syncthreads();
    }
#pragma unroll
    for (int fn = 0; fn < 2; ++fn) {
      long col = tn * 64 + wn + fn * 16 + lrow;
#pragma unroll
      for (int fm = 0; fm < 2; ++fm) {
        long row0 = tm * 64 + wm + fm * 16 + quad * 4;
#pragma unroll
        for (int r = 0; r < 4; ++r) {
          long row = row0 + r;
#pragma unroll
          for (int g = 0; g < 3; ++g)
            G3[row * 1536 + g * 512 + col] = acc[g][fm][fn][r];
        }
      }
    }
  }
}

// ---- level final: gates(G3)+Fpart -> Cbf/H; per-parent h-sum + xh pack -----
__global__ void k_level_final(const float* __restrict__ G3,
                              const float* __restrict__ Fpart,
                              const float* __restrict__ bi,
                              const float* __restrict__ bo,
                              const float* __restrict__ bu,
                              uint16_t* __restrict__ Cbf_out,
                              const uint16_t* __restrict__ Xnext,
                              uint16_t* __restrict__ xh_next) {
  const long p = blockIdx.x;
  const int hq = (threadIdx.x & 127) << 2;
  float4 b_i = *(const float4*)(bi + hq);
  float4 b_o = *(const float4*)(bo + hq);
  float4 b_u = *(const float4*)(bu + hq);
  const float* bip = &b_i.x; const float* bop = &b_o.x;
  const float* bup = &b_u.x;
  float hs[4] = {0.f, 0.f, 0.f, 0.f};
#pragma unroll 4
  for (int k = 0; k < 16; ++k) {
    long row = p * 16 + k;
    float4 gi = *(const float4*)(G3 + row * 1536 + hq);
    float4 go = *(const float4*)(G3 + row * 1536 + 512 + hq);
    float4 gu = *(const float4*)(G3 + row * 1536 + 1024 + hq);
    float4 fp = *(const float4*)(Fpart + row * 512 + hq);
    const float* gip = &gi.x; const float* gop = &go.x;
    const float* gup = &gu.x; const float* fpp = &fp.x;
    ushort4 cw; unsigned short* cwp = &cw.x;
#pragma unroll
    for (int j = 0; j < 4; ++j) {
      float iv = sig_(gip[j] + bip[j]);
      float ov = sig_(gop[j] + bop[j]);
      float uv = tanh_(gup[j] + bup[j]);
      float c  = iv * uv + fpp[j];
      cwp[j] = f2bf(c);
      hs[j] += ov * tanh_(c);
    }
    *(ushort4*)(Cbf_out + row * 512 + hq) = cw;
  }
  *(ushort4*)(xh_next + p * 1024 + hq) = *(const ushort4*)(Xnext + p * 512 + hq);
  ushort4 hw = {f2bf(hs[0]), f2bf(hs[1]), f2bf(hs[2]), f2bf(hs[3])};
  *(ushort4*)(xh_next + p * 1024 + 512 + hq) = hw;
}

// ---- merged: lvl3 fc_combine (256 blks) || lvl2 gates GEMM (32 blks) -------
__global__ __launch_bounds__(256, 3)
void k_fc2_l2g(const uint16_t* __restrict__ CbfU,        // lvl3 C (fc A)
               const uint16_t* __restrict__ Wfc,         // Wf+512, ldb 1024
               const float* __restrict__ Fx,             // FxAll+offs2*512
               const float* __restrict__ bfb,
               float* __restrict__ Fpart,
               const uint16_t* __restrict__ xhB,         // lvl2 A, lda 1024
               const uint16_t* __restrict__ Wg,
               float* __restrict__ G3) {
  __shared__ uint16_t smem[16384];                       // 32 KB pool
  const int tid = threadIdx.x, lane = tid & 63, wave = tid >> 6;
  const int lrow = lane & 15, quad = lane >> 4;
  const int srow = lane >> 3;
  const int scol = (((lane & 7) ^ srow) << 3);
  const int rsw = lrow & 7;
  const int pc[2] = { ((0 + quad) ^ rsw) << 3, ((4 + quad) ^ rsw) << 3 };

  if (blockIdx.x < 256) {
    uint16_t* As = smem;                 // 8 KB
    uint16_t* Bs = smem + 4096;          // 16 KB
    const int wm = (wave >> 1) * 32, wn = (wave & 1) * 64;
    long tm, tn;
    {
      int b = blockIdx.x;
      int x = b & 7, j = b >> 3, per = 8;        // nTm=64
      tn = j & 3; tm = (long)x * per + (j >> 2);
    }
    f32x4 acc[2][4] = {};
    for (int k0 = 0; k0 < 512; k0 += 64) {
#pragma unroll
      for (int j = 0; j < 2; ++j) {
        int grp = wave * 2 + j;
        int row = grp * 8 + srow;
        const uint16_t* gp = CbfU + (tm * 64 + row) * 512L + k0 + scol;
        __builtin_amdgcn_global_load_lds((gbl_void_t*)(uintptr_t)gp,
            (lds_void_t*)&As[grp * 512], 16, 0, 0);
      }
#pragma unroll
      for (int j = 0; j < 4; ++j) {
        int row = wave * 32 + j * 8 + srow;
        const uint16_t* gp = Wfc + (tn * BN + row) * 1024L + k0 + scol;
        __builtin_amdgcn_global_load_lds((gbl_void_t*)(uintptr_t)gp,
            (lds_void_t*)&Bs[(wave * 32 + j * 8) * 64], 16, 0, 0);
      }
      __syncthreads();
#pragma unroll
      for (int h = 0; h < 2; ++h) {
        bf16x8 a[2], b[4];
#pragma unroll
        for (int f = 0; f < 2; ++f)
          a[f] = *(const bf16x8*)&As[(wm + f * 16 + lrow) * 64 + pc[h]];
#pragma unroll
        for (int f = 0; f < 4; ++f)
          b[f] = *(const bf16x8*)&Bs[(wn + f * 16 + lrow) * 64 + pc[h]];
#pragma unroll
        for (int fm = 0; fm < 2; ++fm)
#pragma unroll
          for (int fn = 0; fn < 4; ++fn)
            acc[fm][fn] = __builtin_amdgcn_mfma_f32_16x16x32_bf16(
                a[fm], b[fn], acc[fm][fn], 0, 0, 0);
      }
      __syncthreads();
    }
#pragma unroll
    for (int fm = 0; fm < 2; ++fm) {
      long pg   = tm * 4 + (wm >> 4) + fm;
      long row0 = tm * 64 + wm + fm * 16 + quad * 4;
#pragma unroll
      for (int fn = 0; fn < 4; ++fn) {
        long col = tn * BN + wn + fn * 16 + lrow;
        float fx = Fx[pg * 512 + col] + bfb[col];
        float t = 0.f;
#pragma unroll
        for (int r = 0; r < 4; ++r)
          t += sig_(fx + acc[fm][fn][r]) * bf2f(CbfU[(row0 + r) * 512 + col]);
        t += __shfl_xor(t, 16, 64);
        t += __shfl_xor(t, 32, 64);
        if (quad == 0) Fpart[pg * 512 + col] = t;
      }
    }
  } else {
    uint16_t* As = smem;                 // 8 KB
    uint16_t* Bs = smem + 4096;          // 24 KB
    const int wm = (wave >> 1) * 32, wn = (wave & 1) * 32;
    int b = (int)blockIdx.x - 256;
    long tm = b >> 3, tn = b & 7;
    f32x4 acc[3][2][2] = {};
    for (int k0 = 0; k0 < 1024; k0 += 64) {
#pragma unroll
      for (int j = 0; j < 2; ++j) {
        int grp = wave * 2 + j;
        int row = grp * 8 + srow;
        const uint16_t* gp = xhB + (tm * 64 + row) * 1024L + k0 + scol;
        __builtin_amdgcn_global_load_lds((gbl_void_t*)(uintptr_t)gp,
            (lds_void_t*)&As[grp * 512], 16, 0, 0);
      }
#pragma unroll
      for (int j = 0; j < 6; ++j) {
        int cc = wave * 6 + j;
        int g  = cc >> 3;
        long grow = (long)g * 512 + tn * 64 + (cc & 7) * 8 + srow;
        const uint16_t* gp = Wg + grow * 1024 + k0 + scol;
        __builtin_amdgcn_global_load_lds((gbl_void_t*)(uintptr_t)gp,
            (lds_void_t*)&Bs[cc * 512], 16, 0, 0);
      }
      __syncthreads();
#pragma unroll
      for (int h = 0; h < 2; ++h) {
        bf16x8 a[2];
#pragma unroll
        for (int f = 0; f < 2; ++f)
          a[f] = *(const bf16x8*)&As[(wm + f * 16 + lrow) * 64 + pc[h]];
#pragma unroll
        for (int g = 0; g < 3; ++g) {
          bf16x8 b0 = *(const bf16x8*)&Bs[(g * 64 + wn + lrow) * 64 + pc[h]];
          bf16x8 b1 = *(const bf16x8*)&Bs[(g * 64 + wn + 16 + lrow) * 64 +
                                          pc[h]];
#pragma unroll
          for (int fm = 0; fm < 2; ++fm) {
            acc[g][fm][0] = __builtin_amdgcn_mfma_f32_16x16x32_bf16(
                a[fm], b0, acc[g][fm][0], 0, 0, 0);
            acc[g][fm][1] = __builtin_amdgcn_mfma_f32_16x16x32_bf16(
                a[fm], b1, acc[g][fm][1], 0, 0, 0);
          }
        }
      }
      __syncthreads();
    }
#pragma unroll
    for (int fn = 0; fn < 2; ++fn) {
      long col = tn * 64 + wn + fn * 16 + lrow;
#pragma unroll
      for (int fm = 0; fm < 2; ++fm) {
        long row0 = tm * 64 + wm + fm * 16 + quad * 4;
#pragma unroll
        for (int r = 0; r < 4; ++r) {
          long row = row0 + r;
#pragma unroll
          for (int g = 0; g < 3; ++g)
            G3[row * 1536 + g * 512 + col] = acc[g][fm][fn][r];
        }
      }
    }
  }
}

// ---- merged lvl2 fc_combine (16 blocks) + lvl1 gate dots -------------------
__global__ __launch_bounds__(256)
void k_fcdot(const uint16_t* __restrict__ Cbf,           // CbfU2
             const uint16_t* __restrict__ Wfc,           // Wf + 512
             const float* __restrict__ Fx,
             const float* __restrict__ bfb,
             float* __restrict__ Fpart,
             const uint16_t* __restrict__ xhC,
             const uint16_t* __restrict__ Wg,
             float* __restrict__ Gf) {
  __shared__ uint16_t smem[12288];                       // 24 KB (fc branch)
  const int tid = threadIdx.x, lane = tid & 63, wave = tid >> 6;
  if (blockIdx.x < 16) {
    uint16_t* As = smem;                 // 64*64
    uint16_t* Bs = smem + 4096;          // 128*64
    const int lrow = lane & 15, quad = lane >> 4;
    const int wm = (wave >> 1) * 32, wn = (wave & 1) * 64;
    int b = blockIdx.x;
    long tm = b >> 2, tn = b & 3;        // nTm=4 plain map
    f32x4 acc[2][4] = {};
    const int srow = lane >> 3;
    const int scol = (((lane & 7) ^ srow) << 3);
    const int rsw = lrow & 7;
    const int pc[2] = { ((0 + quad) ^ rsw) << 3, ((4 + quad) ^ rsw) << 3 };
    for (int k0 = 0; k0 < 512; k0 += 64) {
#pragma unroll
      for (int j = 0; j < 2; ++j) {
        int grp = wave * 2 + j;
        int row = grp * 8 + srow;
        const uint16_t* gp = Cbf + (tm * 64 + row) * 512L + k0 + scol;
        __builtin_amdgcn_global_load_lds((gbl_void_t*)(uintptr_t)gp,
            (lds_void_t*)&As[grp * 512], 16, 0, 0);
      }
#pragma unroll
      for (int j = 0; j < 4; ++j) {
        int row = wave * 32 + j * 8 + srow;
        const uint16_t* gp = Wfc + (tn * 128 + row) * 1024L + k0 + scol;
        __builtin_amdgcn_global_load_lds((gbl_void_t*)(uintptr_t)gp,
            (lds_void_t*)&Bs[(wave * 32 + j * 8) * 64], 16, 0, 0);
      }
      __syncthreads();
#pragma unroll
      for (int h = 0; h < 2; ++h) {
        bf16x8 a[2], bb[4];
#pragma unroll
        for (int f = 0; f < 2; ++f)
          a[f] = *(const bf16x8*)&As[(wm + f * 16 + lrow) * 64 + pc[h]];
#pragma unroll
        for (int f = 0; f < 4; ++f)
          bb[f] = *(const bf16x8*)&Bs[(wn + f * 16 + lrow) * 64 + pc[h]];
#pragma unroll
        for (int fm = 0; fm < 2; ++fm)
#pragma unroll
          for (int fn = 0; fn < 4; ++fn)
            acc[fm][fn] = __builtin_amdgcn_mfma_f32_16x16x32_bf16(
                a[fm], bb[fn], acc[fm][fn], 0, 0, 0);
      }
      __syncthreads();
    }
#pragma unroll
    for (int fm = 0; fm < 2; ++fm) {
      long pg   = tm * 4 + (wm >> 4) + fm;
      long row0 = tm * 64 + wm + fm * 16 + quad * 4;
#pragma unroll
      for (int fn = 0; fn < 4; ++fn) {
        long col = tn * 128 + wn + fn * 16 + lrow;
        float fx = Fx[pg * 512 + col] + bfb[col];
        float t = 0.f;
#pragma unroll
        for (int r = 0; r < 4; ++r)
          t += sig_(fx + acc[fm][fn][r]) * bf2f(Cbf[(row0 + r) * 512 + col]);
        t += __shfl_xor(t, 16, 64);
        t += __shfl_xor(t, 32, 64);
        if (quad == 0) Fpart[pg * 512 + col] = t;
      }
    }
  } else {
    int wid = (int)(((long)(blockIdx.x - 16) * 256 + tid) >> 6);
    if (wid >= 16 * 1536) return;
    int m = wid / 1536, n = wid - m * 1536;
    const uint16_t* a = xhC + (long)m * 1024;
    const uint16_t* b = Wg + (long)n * 1024;
    int k0 = lane * 16;
    float s = 0.f;
#pragma unroll
    for (int j = 0; j < 16; j += 4) {
      ushort4 av = *(const ushort4*)(a + k0 + j);
      ushort4 bv = *(const ushort4*)(b + k0 + j);
      s += bf2f(av.x) * bf2f(bv.x) + bf2f(av.y) * bf2f(bv.y)
         + bf2f(av.z) * bf2f(bv.z) + bf2f(av.w) * bf2f(bv.w);
    }
#pragma unroll
    for (int off = 32; off; off >>= 1) s += __shfl_xor(s, off, 64);
    if (lane == 0) Gf[(long)m * 1536 + n] = s;
  }
}

// ---- merged root dots: gates (bf16) + Fc (f32) -----------------------------
__global__ void k_dot_merge(const uint16_t* __restrict__ xhC,
                            const uint16_t* __restrict__ Wg,
                            float* __restrict__ Gf,
                            const float* __restrict__ CupA,
                            const float* __restrict__ WfF,
                            float* __restrict__ Fc) {
  int wid  = (int)((blockIdx.x * (long)blockDim.x + threadIdx.x) >> 6);
  int lane = threadIdx.x & 63;
  if (wid < 1536) {
    const uint16_t* a = xhC;
    const uint16_t* b = Wg + (long)wid * 1024;
    int k0 = lane * 16;
    float s = 0.f;
#pragma unroll
    for (int j = 0; j < 16; j += 4) {
      ushort4 av = *(const ushort4*)(a + k0 + j);
      ushort4 bv = *(const ushort4*)(b + k0 + j);
      s += bf2f(av.x) * bf2f(bv.x) + bf2f(av.y) * bf2f(bv.y)
         + bf2f(av.z) * bf2f(bv.z) + bf2f(av.w) * bf2f(bv.w);
    }
#pragma unroll
    for (int off = 32; off; off >>= 1) s += __shfl_xor(s, off, 64);
    if (lane == 0) Gf[wid] = s;
  } else {
    int w2 = wid - 1536;
    if (w2 >= 16 * 512) return;
    int m = w2 >> 9, n = w2 & 511;
    const float* a = CupA + (long)m * 512;
    const float* b = WfF + (long)n * 1024;
    int k0 = lane * 8;
    float s = 0.f;
#pragma unroll
    for (int j = 0; j < 8; j += 4) {
      float4 av = *(const float4*)(a + k0 + j);
      float4 bv = *(const float4*)(b + k0 + j);
      s += av.x * bv.x + av.y * bv.y + av.z * bv.z + av.w * bv.w;
    }
#pragma unroll
    for (int off = 32; off; off >>= 1) s += __shfl_xor(s, off, 64);
    if (lane == 0) Fc[(long)m * 512 + n] = s;
  }
}

// ---- level-1 tail: final (16 nodes) + h_sum + root xh pack, one block ------
__global__ __launch_bounds__(1024)
void k_lvl1_tail(const float* __restrict__ G,
                 const float* __restrict__ Fpart,
                 const float* __restrict__ bi,
                 const float* __restrict__ bo,
                 const float* __restrict__ bu,
                 float* __restrict__ Cv,               // CupA (16x512)
                 const uint16_t* __restrict__ xroot,   // Xbf row 0
                 uint16_t* __restrict__ xh) {          // xhC row 0 pack
  __shared__ float Hl[16 * 512];                       // 32 KB
  const int tid = threadIdx.x;
#pragma unroll
  for (int it = 0; it < 2; ++it) {
    int idx = it * 1024 + tid;
    int p = idx >> 7, hq = (idx & 127) << 2;
    const float* g = G + (long)p * 1536;
    float4 gi = *(const float4*)(g + hq);
    float4 go = *(const float4*)(g + 512 + hq);
    float4 gu = *(const float4*)(g + 1024 + hq);
    float4 b_i = *(const float4*)(bi + hq);
    float4 b_o = *(const float4*)(bo + hq);
    float4 b_u = *(const float4*)(bu + hq);
    float4 fp = *(const float4*)(Fpart + (long)p * 512 + hq);
    const float* gip = &gi.x; const float* gop = &go.x;
    const float* gup = &gu.x; const float* bip = &b_i.x;
    const float* bop = &b_o.x; const float* bup = &b_u.x;
    const float* fpp = &fp.x;
    float4 hv, cv;
    float* hvp = &hv.x; float* cvp = &cv.x;
#pragma unroll
    for (int j = 0; j < 4; ++j) {
      float iv = sig_(gip[j] + bip[j]);
      float ov = sig_(gop[j] + bop[j]);
      float uv = tanh_(gup[j] + bup[j]);
      float c  = iv * uv + fpp[j];
      cvp[j] = c;
      hvp[j] = ov * tanh_(c);
    }
    *(float4*)(Cv + (long)p * 512 + hq) = cv;
    *(float4*)(&Hl[p * 512 + hq]) = hv;
  }
  __syncthreads();
  if (tid < 128) {
    int hq = tid << 2;
    float4 s = {0.f, 0.f, 0.f, 0.f};
#pragma unroll
    for (int b = 0; b < 16; ++b) {
      float4 v = *(const float4*)(&Hl[b * 512 + hq]);
      s.x += v.x; s.y += v.y; s.z += v.z; s.w += v.w;
    }
    *(ushort4*)(xh + hq) = *(const ushort4*)(xroot + hq);
    ushort4 hw = {f2bf(s.x), f2bf(s.y), f2bf(s.z), f2bf(s.w)};
    *(ushort4*)(xh + 512 + hq) = hw;
  }
}

// ---- fused root tail: combine (16 children) + final, 1 block, 128 thr ------
__global__ void k_root_tail(const float* __restrict__ Fc,
                            const float* __restrict__ Fx,
                            const float* __restrict__ bfb,
                            const float* __restrict__ Cc,
                            const float* __restrict__ G,
                            const float* __restrict__ bi,
                            const float* __restrict__ bo,
                            const float* __restrict__ bu,
                            float* __restrict__ H, float* __restrict__ Cv) {
  int hq = (threadIdx.x & 127) << 2;
  float4 fxv = *(const float4*)(Fx + hq);
  float4 bfv = *(const float4*)(bfb + hq);
  float fx0 = fxv.x + bfv.x, fx1 = fxv.y + bfv.y;
  float fx2 = fxv.z + bfv.z, fx3 = fxv.w + bfv.w;
  float a0 = 0.f, a1 = 0.f, a2 = 0.f, a3 = 0.f;
#pragma unroll 4
  for (int b = 0; b < 16; ++b) {
    float4 f = *(const float4*)(Fc + (long)b * 512 + hq);
    float4 c = *(const float4*)(Cc + (long)b * 512 + hq);
    a0 += sig_(fx0 + f.x) * c.x;
    a1 += sig_(fx1 + f.y) * c.y;
    a2 += sig_(fx2 + f.z) * c.z;
    a3 += sig_(fx3 + f.w) * c.w;
  }
  float fpp[4] = {a0, a1, a2, a3};
  float4 gi = *(const float4*)(G + hq);
  float4 go = *(const float4*)(G + 512 + hq);
  float4 gu = *(const float4*)(G + 1024 + hq);
  float4 b_i = *(const float4*)(bi + hq);
  float4 b_o = *(const float4*)(bo + hq);
  float4 b_u = *(const float4*)(bu + hq);
  const float* gip = &gi.x; const float* gop = &go.x; const float* gup = &gu.x;
  const float* bip = &b_i.x; const float* bop = &b_o.x; const float* bup = &b_u.x;
  float4 hv, cv;
  float* hvp = &hv.x; float* cvp = &cv.x;
#pragma unroll
  for (int j = 0; j < 4; ++j) {
    float iv = sig_(gip[j] + bip[j]);
    float ov = sig_(gop[j] + bop[j]);
    float uv = tanh_(gup[j] + bup[j]);
    float c  = iv * uv + fpp[j];
    cvp[j] = c;
    hvp[j] = ov * tanh_(c);
  }
  *(float4*)(H  + hq) = hv;
  *(float4*)(Cv + hq) = cv;
}

// ---------------------------------------------------------------------------
extern "C" void kernel_launch(void* const* d_in, const int* in_sizes, int n_in,
                              void* d_out, int out_size, void* d_ws, size_t ws_size,
                              hipStream_t stream) {
  const float* x    = (const float*)d_in[0];
  const float* wi_w = (const float*)d_in[1];
  const float* wi_b = (const float*)d_in[2];
  const float* wf_w = (const float*)d_in[3];
  const float* wf_b = (const float*)d_in[4];
  const float* wo_w = (const float*)d_in[5];
  const float* wo_b = (const float*)d_in[6];
  const float* wu_w = (const float*)d_in[7];
  const float* wu_b = (const float*)d_in[8];
  (void)in_sizes; (void)n_in; (void)out_size; (void)ws_size;

  static const long offs[5] = {0, 1, 17, 273, 4369};
  const long NTOT = 69905;

  // ---- workspace ----
  char* ws = (char*)d_ws;
  size_t off = 0;
  auto alloc = [&](size_t bytes) -> void* {
    void* p = ws + off;
    off += (bytes + 255) & ~(size_t)255;
    return p;
  };
  uint16_t* Xbf   = (uint16_t*)alloc(NTOT * 512 * 2);
  uint16_t* Wgw   = (uint16_t*)alloc((size_t)2048 * 1024 * 2);
  uint16_t* Wg    = Wgw;
  uint16_t* Wf    = Wgw + (size_t)1536 * 1024;
  float*    FxAll = (float*)alloc((size_t)4480 * 512 * 4);
  uint16_t* Cbf   = (uint16_t*)alloc((size_t)65536 * 512 * 2);
  uint16_t* CbfU  = (uint16_t*)alloc((size_t)4096 * 512 * 2);
  uint16_t* CbfU2 = (uint16_t*)alloc((size_t)256 * 512 * 2);
  uint16_t* xhA   = (uint16_t*)alloc((size_t)4096 * 1024 * 2);
  uint16_t* xhB   = (uint16_t*)alloc((size_t)256 * 1024 * 2);
  uint16_t* xhC   = (uint16_t*)alloc((size_t)16 * 1024 * 2);
  float*    Fpart = (float*)alloc((size_t)4096 * 512 * 4);
  float*    G3    = (float*)alloc((size_t)4096 * 1536 * 4);
  float*    Gf    = (float*)alloc((size_t)16 * 1536 * 4);
  float*    Fc    = (float*)alloc((size_t)16 * 512 * 4);
  float*    CupA  = (float*)alloc((size_t)16 * 512 * 4);

  // ---- merged convert: all x + 4 weight matrices ----
  {
    long n4x = NTOT * 512 / 4;
    k_conv_all<<<8192, 256, 0, stream>>>(
        (const float4*)x, (ushort4*)Xbf, n4x,
        (const float4*)wi_w, (const float4*)wo_w,
        (const float4*)wu_w, (const float4*)wf_w, (ushort4*)Wgw);
  }

  // ---- leaf level + FxAll gemm in ONE launch (4096 + 140 blocks) ----
  k_leaf_fx<<<4236, 256, 0, stream>>>(
      Xbf + offs[4] * 512, Wg, wi_b, wo_b, wu_b,
      Cbf, Xbf + offs[3] * 512, xhA,
      Xbf, Wf, FxAll);

  // ---- leaf fc (2048) || lvl3 gates (512) in ONE launch ----
  k_fc4_l3g<<<2560, 256, 0, stream>>>(
      Cbf, Wf + 512, FxAll + offs[3] * 512, wf_b, Fpart,
      xhA, Wg, G3);

  // ---- lvl3 final: gates+Fpart -> CbfU, xhB (256 parents) ----
  k_level_final<<<256, 128, 0, stream>>>(
      G3, Fpart, wi_b, wo_b, wu_b, CbfU, Xbf + offs[2] * 512, xhB);

  // ---- lvl3 fc (256) || lvl2 gates (32) in ONE launch ----
  k_fc2_l2g<<<288, 256, 0, stream>>>(
      CbfU, Wf + 512, FxAll + offs[2] * 512, wf_b, Fpart,
      xhB, Wg, G3);

  // ---- lvl2 final: gates+Fpart -> CbfU2, xhC (16 parents) ----
  k_level_final<<<16, 128, 0, stream>>>(
      G3, Fpart, wi_b, wo_b, wu_b, CbfU2, Xbf + offs[1] * 512, xhC);

  // ---- lvl2 fc + lvl1 gate dots in ONE launch (16 + 6144 blocks) ----
  k_fcdot<<<6160, 256, 0, stream>>>(CbfU2, Wf + 512,
                                    FxAll + offs[1] * 512, wf_b, Fpart,
                                    xhC, Wg, Gf);

  // ---- level 1 tail (final + hsum + root pack) ----
  k_lvl1_tail<<<1, 1024, 0, stream>>>(Gf, Fpart, wi_b, wo_b, wu_b,
                                      CupA, Xbf + offs[0] * 512, xhC);

  // ---- level 0 (root): merged gate-dot + Fc-dot, then fused tail ----
  {
    long waves = 1536 + 16L * 512;       // 9728 waves = 2432 blocks exactly
    k_dot_merge<<<(int)(waves / 4), 256, 0, stream>>>(
        xhC, Wg, Gf, CupA, wf_w + 512, Fc);
  }
  k_root_tail<<<1, 128, 0, stream>>>(Fc, FxAll, wf_b, CupA, Gf,
                                     wi_b, wo_b, wu_b,
                                     (float*)d_out, (float*)d_out + 512);
}